// Round 5
// baseline (507.279 us; speedup 1.0000x reference)
//
#include <hip/hip_runtime.h>
#include <math.h>

#define H_ 256
#define W_ 256
#define HW_ 65536
#define BHW_ 131072   // B*H*W, B=2
#define NPC 8388608   // BHW_*64

__device__ __forceinline__ float geluf(float x) {
    const float k0 = 0.7978845608028654f; // sqrt(2/pi)
    return 0.5f * x * (1.f + tanhf(k0 * (x + 0.044715f * x * x * x)));
}
__device__ __forceinline__ float siluf(float x) {
    return x / (1.f + expf(-x));
}

// ---------- fused Poisson: div + 20 Jacobi iters ----------
__global__ __launch_bounds__(256) void k_poisson(const float* __restrict__ x,
                                                 float* __restrict__ gray) {
    __shared__ float u[56 * 57];
    __shared__ float dv[56 * 57];
    int bid = blockIdx.x;
    int b = bid >> 8, t = bid & 255;
    int qy = t >> 4, qx = t & 15;
    int y0i = qy << 4, x0i = qx << 4;
    int ys = max(y0i - 20, 0), ye = min(y0i + 35, 255);
    int xs = max(x0i - 20, 0), xe = min(x0i + 35, 255);
    int Ht = ye - ys + 1, Wt = xe - xs + 1;   // <= 56
    int ty = threadIdx.x >> 5, tx = threadIdx.x & 31;   // 8 x 32
    const float* x5 = x + ((size_t)(b * 9 + 5) << 16);
    const float* x6 = x + ((size_t)(b * 9 + 6) << 16);

    for (int yy = ty; yy < Ht; yy += 8)
        for (int xx = tx; xx < Wt; xx += 32) {
            int gy = ys + yy, gx = xs + xx;
            int i00 = (gy << 8) + gx;
            float v5 = x5[i00], v6 = x6[i00];
            float d = -0.5f * (v5 + v6) + 0.5f * (v5 - v6);
            if (gx > 0) d += 0.5f * (x5[i00 - 1] + x6[i00 - 1]);
            if (gy > 0) d -= 0.5f * (x5[i00 - 256] - x6[i00 - 256]);
            dv[yy * 57 + xx] = d;
            u[yy * 57 + xx] = 0.f;
        }
    __syncthreads();

    float nv[7][2];
    for (int it = 0; it < 20; ++it) {
        #pragma unroll
        for (int i = 0; i < 7; ++i) {
            int yy = ty + i * 8;
            #pragma unroll
            for (int j = 0; j < 2; ++j) {
                int xx = tx + j * 32;
                if (yy < Ht && xx < Wt) {
                    int ym = yy > 0 ? yy - 1 : 0, yp = yy < Ht - 1 ? yy + 1 : Ht - 1;
                    int xm = xx > 0 ? xx - 1 : 0, xp = xx < Wt - 1 ? xx + 1 : Wt - 1;
                    nv[i][j] = (u[ym * 57 + xx] + u[yp * 57 + xx] +
                                u[yy * 57 + xm] + u[yy * 57 + xp] - dv[yy * 57 + xx]) * 0.25f;
                }
            }
        }
        __syncthreads();
        #pragma unroll
        for (int i = 0; i < 7; ++i) {
            int yy = ty + i * 8;
            #pragma unroll
            for (int j = 0; j < 2; ++j) {
                int xx = tx + j * 32;
                if (yy < Ht && xx < Wt) u[yy * 57 + xx] = nv[i][j];
            }
        }
        __syncthreads();
    }

    int oy = threadIdx.x >> 4, ox = threadIdx.x & 15;
    int gy = y0i + oy, gx = x0i + ox;
    gray[((size_t)b << 16) + (gy << 8) + gx] = u[(gy - ys) * 57 + (gx - xs)];
}

// ---------- conv1: 7 -> 32, silu; wave = 64 px, weights via s_load ----------
__global__ __launch_bounds__(256) void k_conv1(const float* __restrict__ x,
        const float* __restrict__ wT, const float* __restrict__ bias,
        float* __restrict__ out) {
    int wid = (blockIdx.x * 256 + threadIdx.x) >> 6;
    int lane = threadIdx.x & 63;
    int pix0 = wid << 6;
    int b = pix0 >> 16, hw0 = pix0 & 65535;
    int h = hw0 >> 8, w0 = hw0 & 255;
    float acc[32];
    #pragma unroll
    for (int o = 0; o < 32; ++o) acc[o] = bias[o];
    const float* inb = x + ((size_t)(b * 9) << 16);
    #pragma unroll
    for (int kh = 0; kh < 3; ++kh) {
        int y = h + kh - 1;
        if ((unsigned)y >= 256u) continue;
        #pragma unroll
        for (int kw = 0; kw < 3; ++kw) {
            int xx = w0 + lane + kw - 1;
            bool valid = (unsigned)xx < 256u;
            int xc = min(max(xx, 0), 255);
            const float* p0 = inb + (y << 8) + xc;
            #pragma unroll
            for (int ci = 0; ci < 7; ++ci) {
                float v = p0[ci << 16];
                v = valid ? v : 0.f;
                const float* wr = wT + (ci * 9 + kh * 3 + kw) * 32;
                #pragma unroll
                for (int o = 0; o < 32; ++o) acc[o] = fmaf(v, wr[o], acc[o]);
            }
        }
    }
    #pragma unroll
    for (int o = 0; o < 32; ++o)
        out[((size_t)(b * 32 + o) << 16) + hw0 + lane] = siluf(acc[o]);
}

// ---------- conv2: 32 -> 32, silu ----------
__global__ __launch_bounds__(256) void k_conv2(const float* __restrict__ in,
        const float* __restrict__ wT, const float* __restrict__ bias,
        float* __restrict__ out) {
    int wid = (blockIdx.x * 256 + threadIdx.x) >> 6;
    int lane = threadIdx.x & 63;
    int pix0 = wid << 6;
    int b = pix0 >> 16, hw0 = pix0 & 65535;
    int h = hw0 >> 8, w0 = hw0 & 255;
    float acc[32];
    #pragma unroll
    for (int o = 0; o < 32; ++o) acc[o] = bias[o];
    const float* inb = in + ((size_t)(b * 32) << 16);
    #pragma unroll
    for (int kh = 0; kh < 3; ++kh) {
        int y = h + kh - 1;
        if ((unsigned)y >= 256u) continue;
        #pragma unroll
        for (int kw = 0; kw < 3; ++kw) {
            int xx = w0 + lane + kw - 1;
            bool valid = (unsigned)xx < 256u;
            int xc = min(max(xx, 0), 255);
            const float* p0 = inb + (y << 8) + xc;
            #pragma unroll 4
            for (int ci = 0; ci < 32; ++ci) {
                float v = p0[ci << 16];
                v = valid ? v : 0.f;
                const float* wr = wT + (ci * 9 + kh * 3 + kw) * 32;
                #pragma unroll
                for (int o = 0; o < 32; ++o) acc[o] = fmaf(v, wr[o], acc[o]);
            }
        }
    }
    #pragma unroll
    for (int o = 0; o < 32; ++o)
        out[((size_t)(b * 32 + o) << 16) + hw0 + lane] = siluf(acc[o]);
}

// ---------- conv3: 32 -> 3 ----------
__global__ __launch_bounds__(256) void k_conv3(const float* __restrict__ in,
        const float* __restrict__ wT, const float* __restrict__ bias,
        float* __restrict__ out) {
    int wid = (blockIdx.x * 256 + threadIdx.x) >> 6;
    int lane = threadIdx.x & 63;
    int pix0 = wid << 6;
    int b = pix0 >> 16, hw0 = pix0 & 65535;
    int h = hw0 >> 8, w0 = hw0 & 255;
    float acc[3];
    #pragma unroll
    for (int o = 0; o < 3; ++o) acc[o] = bias[o];
    const float* inb = in + ((size_t)(b * 32) << 16);
    #pragma unroll
    for (int kh = 0; kh < 3; ++kh) {
        int y = h + kh - 1;
        if ((unsigned)y >= 256u) continue;
        #pragma unroll
        for (int kw = 0; kw < 3; ++kw) {
            int xx = w0 + lane + kw - 1;
            bool valid = (unsigned)xx < 256u;
            int xc = min(max(xx, 0), 255);
            const float* p0 = inb + (y << 8) + xc;
            #pragma unroll 8
            for (int ci = 0; ci < 32; ++ci) {
                float v = p0[ci << 16];
                v = valid ? v : 0.f;
                const float* wr = wT + (ci * 9 + kh * 3 + kw) * 3;
                #pragma unroll
                for (int o = 0; o < 3; ++o) acc[o] = fmaf(v, wr[o], acc[o]);
            }
        }
    }
    #pragma unroll
    for (int o = 0; o < 3; ++o)
        out[((size_t)(b * 3 + o) << 16) + hw0 + lane] = acc[o];
}

// ---------- fused aproj + depthwise + gelu: tile 8x8, halo 1 ----------
__global__ __launch_bounds__(256) void k_adw(const float* __restrict__ x,
        const float* __restrict__ Wa, const float* __restrict__ ba,
        const float* __restrict__ dwW, float* __restrict__ a2) {
    __shared__ float at[100][64];
    int tid = threadIdx.x;
    int bid = blockIdx.x;
    int b = bid >> 10, tb = bid & 1023;
    int ty0 = (tb >> 5) << 3, tx0 = (tb & 31) << 3;
    const float* g0p = x + ((size_t)(b * 9 + 7) << 16);
    const float* g1p = x + ((size_t)(b * 9 + 8) << 16);
    const float* g2p = x + ((size_t)(b * 9 + 5) << 16);
    const float* g3p = x + ((size_t)(b * 9 + 6) << 16);
    int c = tid & 63;
    float w0 = Wa[c], w1 = Wa[64 + c], w2 = Wa[128 + c], w3 = Wa[192 + c];
    float bb = ba[c];
    #pragma unroll
    for (int rep = 0; rep < 25; ++rep) {
        int pos = rep * 4 + (tid >> 6);
        int py = pos / 10, pxx = pos - py * 10;
        int gy = ty0 - 1 + py, gx = tx0 - 1 + pxx;
        float v = 0.f;
        if ((unsigned)gy < 256u && (unsigned)gx < 256u) {
            int ii = (gy << 8) + gx;
            float tv = bb + g0p[ii] * w0 + g1p[ii] * w1 + g2p[ii] * w2 + g3p[ii] * w3;
            v = geluf(tv);
        }
        at[pos][c] = v;
    }
    __syncthreads();
    float dwr[9];
    #pragma unroll
    for (int k = 0; k < 9; ++k) dwr[k] = dwW[k * 64 + c];
    int pgrp = tid >> 6;
    #pragma unroll
    for (int i = 0; i < 16; ++i) {
        int pl = pgrp * 16 + i;
        int pyl = pl >> 3, pxl = pl & 7;
        float s = 0.f;
        #pragma unroll
        for (int kh = 0; kh < 3; ++kh)
            #pragma unroll
            for (int kw = 0; kw < 3; ++kw)
                s += at[(pyl + kh) * 10 + (pxl + kw)][c] * dwr[kh * 3 + kw];
        int gy = ty0 + pyl, gx = tx0 + pxl;
        a2[(((size_t)(b << 16) + (gy << 8) + gx) << 6) + c] = geluf(s);
    }
}

// ---------- xg = core @ W_in + b_in, NHWC ----------
__global__ void k_xproj(const float* __restrict__ x, const float* __restrict__ gray,
                        const float* __restrict__ recon, const float* __restrict__ W,
                        const float* __restrict__ bias, float* __restrict__ xg) {
    int idx = blockIdx.x * blockDim.x + threadIdx.x;
    if (idx >= NPC) return;
    int pix = idx >> 6, c = idx & 63;
    int b = pix >> 16, hw = pix & 65535;
    float c0 = x[((size_t)(b * 9 + 0) << 16) + hw];
    float c1 = x[((size_t)(b * 9 + 1) << 16) + hw];
    float c2 = x[((size_t)(b * 9 + 2) << 16) + hw];
    float c3 = gray[pix];
    float c4 = recon[((size_t)(b * 3 + 0) << 16) + hw];
    float c5 = recon[((size_t)(b * 3 + 1) << 16) + hw];
    float c6 = recon[((size_t)(b * 3 + 2) << 16) + hw];
    float v = bias[c] + c0 * W[c] + c1 * W[64 + c] + c2 * W[128 + c] + c3 * W[192 + c]
            + c4 * W[256 + c] + c5 * W[320 + c] + c6 * W[384 + c];
    xg[idx] = v;
}

// ---------- weight prep ----------
__device__ __forceinline__ float wcomb(const float* Woff, const float* Wmask, int c, int j) {
    return j < 72 ? Woff[c * 72 + j] : (j < 108 ? Wmask[c * 36 + (j - 72)] : 0.f);
}

__global__ void k_prep(const float* __restrict__ Woff, const float* __restrict__ boff,
                       const float* __restrict__ Wmask, const float* __restrict__ bmask,
                       const float* __restrict__ Wout, const float* __restrict__ rw1,
                       const float* __restrict__ rw2, const float* __restrict__ rw3,
                       float* __restrict__ WqA, float* __restrict__ WqB,
                       float* __restrict__ Woq, float* __restrict__ bcomb,
                       float* __restrict__ wT1, float* __restrict__ wT2,
                       float* __restrict__ wT3) {
    int tid = threadIdx.x;
    int lane = tid & 63, seg = tid >> 6;
    for (int i = seg; i < 16; i += 4) {
        float4 qa, qb, qo;
        qa.x = wcomb(Woff, Wmask, 4 * i + 0, lane);
        qa.y = wcomb(Woff, Wmask, 4 * i + 1, lane);
        qa.z = wcomb(Woff, Wmask, 4 * i + 2, lane);
        qa.w = wcomb(Woff, Wmask, 4 * i + 3, lane);
        qb.x = wcomb(Woff, Wmask, 4 * i + 0, lane + 64);
        qb.y = wcomb(Woff, Wmask, 4 * i + 1, lane + 64);
        qb.z = wcomb(Woff, Wmask, 4 * i + 2, lane + 64);
        qb.w = wcomb(Woff, Wmask, 4 * i + 3, lane + 64);
        qo.x = Wout[(4 * i + 0) * 64 + lane];
        qo.y = Wout[(4 * i + 1) * 64 + lane];
        qo.z = Wout[(4 * i + 2) * 64 + lane];
        qo.w = Wout[(4 * i + 3) * 64 + lane];
        ((float4*)WqA)[i * 64 + lane] = qa;
        ((float4*)WqB)[i * 64 + lane] = qb;
        ((float4*)Woq)[i * 64 + lane] = qo;
    }
    if (tid < 128) bcomb[tid] = tid < 72 ? boff[tid] : (tid < 108 ? bmask[tid - 72] : 0.f);
    for (int j = tid; j < 63 * 32; j += 256) {
        int jj = j >> 5, o = j & 31;
        wT1[j] = rw1[o * 63 + jj];
    }
    for (int j = tid; j < 288 * 32; j += 256) {
        int jj = j >> 5, o = j & 31;
        wT2[j] = rw2[o * 288 + jj];
    }
    for (int j = tid; j < 288 * 3; j += 256) {
        int jj = j / 3, o = j - jj * 3;
        wT3[j] = rw3[o * 288 + jj];
    }
}

// ---------- DCNv3 core v5: 4 px/wave, float2 gather, 64-bit element addressing ----------
__global__ __launch_bounds__(256, 4) void k_dcn(
        const float* __restrict__ a2, const float* __restrict__ xg,
        const float* __restrict__ WqA, const float* __restrict__ WqB,
        const float* __restrict__ Woq, const float* __restrict__ bcomb,
        const float* __restrict__ bout, float* __restrict__ out) {
    __shared__ __attribute__((aligned(16))) float bufA[16][64];
    __shared__ __attribute__((aligned(16))) float offs[16][72];
    __shared__ float pms[16][36];
    __shared__ float invs[16][4];
    __shared__ __attribute__((aligned(16))) float taps[16][36][8];
    float (*outs)[65] = (float (*)[65])&taps[0][0][0];

    int tid = threadIdx.x;
    int wave = tid >> 6, lane = tid & 63;
    int pixbase = blockIdx.x << 4;
    int b = pixbase >> 16, hw0 = pixbase & 65535;
    int h = hw0 >> 8, w0 = hw0 & 255;
    int pw = wave << 2;

    #pragma unroll
    for (int p = 0; p < 4; ++p)
        bufA[pw + p][lane] = a2[((size_t)(pixbase + pw + p) << 6) + lane];

    // B: combined off(72)+mask(36)+pad projection, quad weights
    float acc0[4], acc1[4];
    {
        float b0 = bcomb[lane], b1 = bcomb[64 + lane];
        #pragma unroll
        for (int p = 0; p < 4; ++p) { acc0[p] = b0; acc1[p] = b1; }
        #pragma unroll 4
        for (int i = 0; i < 16; ++i) {
            float4 qa = ((const float4*)WqA)[i * 64 + lane];
            float4 qb = ((const float4*)WqB)[i * 64 + lane];
            #pragma unroll
            for (int p = 0; p < 4; ++p) {
                float4 av = ((const float4*)&bufA[pw + p][0])[i];
                acc0[p] += av.x * qa.x + av.y * qa.y + av.z * qa.z + av.w * qa.w;
                acc1[p] += av.x * qb.x + av.y * qb.y + av.z * qb.z + av.w * qb.w;
            }
        }
    }
    // C: scatter; exp for mask logits (shift-free softmax)
    #pragma unroll
    for (int p = 0; p < 4; ++p) offs[pw + p][lane] = acc0[p];
    if (lane < 8) {
        #pragma unroll
        for (int p = 0; p < 4; ++p) offs[pw + p][64 + lane] = acc1[p];
    } else if (lane < 44) {
        #pragma unroll
        for (int p = 0; p < 4; ++p) pms[pw + p][lane - 8] = __expf(acc1[p]);
    }
    // D: per (px,g) reciprocal sums
    if (lane < 16) {
        int p = lane >> 2, g = lane & 3;
        const float* m = &pms[pw + p][g * 9];
        float s = m[0]+m[1]+m[2]+m[3]+m[4]+m[5]+m[6]+m[7]+m[8];
        invs[pw + p][g] = 1.f / s;
    }
    // E: tap descriptors (spatial index + fused weight), 144 jobs over 64 lanes
    #pragma unroll
    for (int rep = 0; rep < 3; ++rep) {
        int idx = rep * 64 + lane;
        if (idx < 144) {
            int p = idx / 36, j = idx - p * 36;
            int px = pw + p;
            int g = j / 9, k = j - g * 9;
            float2 oxy = ((const float2*)&offs[px][0])[j];
            float pm = pms[px][j] * invs[px][g];
            float ly = (float)(h + k / 3 - 1) + oxy.x;
            float lx = (float)(w0 + px + (k % 3) - 1) + oxy.y;
            float y0f = floorf(ly), x0f = floorf(lx);
            float wy = ly - y0f, wx = lx - x0f;
            int iy0 = (int)y0f, ix0 = (int)x0f;
            int base = b << 16;
            float4 t01, t23;
            {
                int yi = iy0, xi = ix0;
                float wgt = (1.f - wy) * (1.f - wx) * pm;
                if (yi < 0 || yi > 255 || xi < 0 || xi > 255) wgt = 0.f;
                int yc = min(max(yi, 0), 255), xc = min(max(xi, 0), 255);
                t01.x = __int_as_float(base + (yc << 8) + xc); t01.y = wgt;
            }
            {
                int yi = iy0, xi = ix0 + 1;
                float wgt = (1.f - wy) * wx * pm;
                if (yi < 0 || yi > 255 || xi < 0 || xi > 255) wgt = 0.f;
                int yc = min(max(yi, 0), 255), xc = min(max(xi, 0), 255);
                t01.z = __int_as_float(base + (yc << 8) + xc); t01.w = wgt;
            }
            {
                int yi = iy0 + 1, xi = ix0;
                float wgt = wy * (1.f - wx) * pm;
                if (yi < 0 || yi > 255 || xi < 0 || xi > 255) wgt = 0.f;
                int yc = min(max(yi, 0), 255), xc = min(max(xi, 0), 255);
                t23.x = __int_as_float(base + (yc << 8) + xc); t23.y = wgt;
            }
            {
                int yi = iy0 + 1, xi = ix0 + 1;
                float wgt = wy * wx * pm;
                if (yi < 0 || yi > 255 || xi < 0 || xi > 255) wgt = 0.f;
                int yc = min(max(yi, 0), 255), xc = min(max(xi, 0), 255);
                t23.z = __int_as_float(base + (yc << 8) + xc); t23.w = wgt;
            }
            ((float4*)&taps[px][j][0])[0] = t01;
            ((float4*)&taps[px][j][0])[1] = t23;
        }
    }
    // F: float2 gather; lane = px2*32 + cp (cp = channel pair 0..31, g = cp>>3)
    {
        int cp = lane & 31, px2 = lane >> 5;
        int g9 = (cp >> 3) * 9;
        const float2* xg2 = (const float2*)xg;
        #pragma unroll
        for (int pr = 0; pr < 2; ++pr) {
            int px = pw + pr * 2 + px2;
            float ax = 0.f, ay = 0.f;
            const float4* tp4 = (const float4*)&taps[px][g9][0];
            #pragma unroll
            for (int k = 0; k < 9; ++k) {
                float4 d0 = tp4[2 * k], d1 = tp4[2 * k + 1];
                {
                    float2 v = xg2[((size_t)(unsigned)__float_as_int(d0.x) << 5) + cp];
                    ax = fmaf(d0.y, v.x, ax); ay = fmaf(d0.y, v.y, ay);
                }
                {
                    float2 v = xg2[((size_t)(unsigned)__float_as_int(d0.z) << 5) + cp];
                    ax = fmaf(d0.w, v.x, ax); ay = fmaf(d0.w, v.y, ay);
                }
                {
                    float2 v = xg2[((size_t)(unsigned)__float_as_int(d1.x) << 5) + cp];
                    ax = fmaf(d1.y, v.x, ax); ay = fmaf(d1.y, v.y, ay);
                }
                {
                    float2 v = xg2[((size_t)(unsigned)__float_as_int(d1.z) << 5) + cp];
                    ax = fmaf(d1.w, v.x, ax); ay = fmaf(d1.w, v.y, ay);
                }
            }
            // G: stage accs over dead a2 staging (wave-local rows)
            *(float2*)&bufA[px][cp * 2] = make_float2(ax, ay);
        }
    }
    __syncthreads();   // taps dead in all waves before outs overlay

    // H: out projection, quad weights
    {
        float o4[4];
        float bo = bout[lane];
        #pragma unroll
        for (int p = 0; p < 4; ++p) o4[p] = bo;
        #pragma unroll 4
        for (int i = 0; i < 16; ++i) {
            float4 wq = ((const float4*)Woq)[i * 64 + lane];
            #pragma unroll
            for (int p = 0; p < 4; ++p) {
                float4 av = ((const float4*)&bufA[pw + p][0])[i];
                o4[p] += av.x * wq.x + av.y * wq.y + av.z * wq.z + av.w * wq.w;
            }
        }
        #pragma unroll
        for (int p = 0; p < 4; ++p) outs[pw + p][lane] = o4[p];
    }
    __syncthreads();

    // transposed NCHW write
    int cq = tid >> 4, px = tid & 15;
    size_t rowb = ((size_t)(b * 64) << 16) + hw0 + px;
    #pragma unroll
    for (int rep = 0; rep < 4; ++rep) {
        int c = cq + rep * 16;
        out[rowb + ((size_t)c << 16)] = outs[px][c];
    }
}

extern "C" void kernel_launch(void* const* d_in, const int* in_sizes, int n_in,
                              void* d_out, int out_size, void* d_ws, size_t ws_size,
                              hipStream_t stream) {
    const float* x      = (const float*)d_in[0];
    const float* rw1    = (const float*)d_in[1];
    const float* rb1    = (const float*)d_in[2];
    const float* rw2    = (const float*)d_in[3];
    const float* rb2    = (const float*)d_in[4];
    const float* rw3    = (const float*)d_in[5];
    const float* rb3    = (const float*)d_in[6];
    const float* W_in   = (const float*)d_in[7];
    const float* b_in   = (const float*)d_in[8];
    const float* W_aop  = (const float*)d_in[9];
    const float* b_aop  = (const float*)d_in[10];
    const float* dw     = (const float*)d_in[11];
    const float* W_off  = (const float*)d_in[12];
    const float* b_off  = (const float*)d_in[13];
    const float* W_mask = (const float*)d_in[14];
    const float* b_mask = (const float*)d_in[15];
    const float* W_out  = (const float*)d_in[16];
    const float* b_out  = (const float*)d_in[17];
    float* out = (float*)d_out;

    float* ws = (float*)d_ws;
    float* WqA   = ws;                        // 4096
    float* WqB   = WqA + 4096;                // 4096
    float* Woq   = WqB + 4096;                // 4096
    float* bcomb = Woq + 4096;                // 128
    float* wT1   = bcomb + 128;               // 2016
    float* wT2   = wT1 + 2016;                // 9216
    float* wT3   = wT2 + 9216;                // 864
    float* gray  = wT3 + 864 + 40;            // pad: keep 16B align downstream
    float* h1    = gray + BHW_;               // 4194304
    float* h2    = h1 + (size_t)BHW_ * 32;    // 4194304
    float* recon = h2 + (size_t)BHW_ * 32;    // 393216
    float* a2    = recon + (size_t)BHW_ * 3;  // 8388608
    float* xg    = a2 + (size_t)NPC;          // 8388608

    dim3 blk(256);

    k_prep<<<dim3(1), blk, 0, stream>>>(W_off, b_off, W_mask, b_mask, W_out,
                                        rw1, rw2, rw3,
                                        WqA, WqB, Woq, bcomb, wT1, wT2, wT3);
    k_poisson<<<dim3(512), blk, 0, stream>>>(x, gray);
    k_conv1<<<dim3(BHW_ / 256), blk, 0, stream>>>(x, wT1, rb1, h1);
    k_conv2<<<dim3(BHW_ / 256), blk, 0, stream>>>(h1, wT2, rb2, h2);
    k_conv3<<<dim3(BHW_ / 256), blk, 0, stream>>>(h2, wT3, rb3, recon);
    k_adw<<<dim3(BHW_ / 64), blk, 0, stream>>>(x, W_aop, b_aop, dw, a2);
    k_xproj<<<dim3(NPC / 256), blk, 0, stream>>>(x, gray, recon, W_in, b_in, xg);
    k_dcn<<<dim3(BHW_ / 16), blk, 0, stream>>>(a2, xg, WqA, WqB, Woq, bcomb, b_out, out);
}

// Round 6
// 330.256 us; speedup vs baseline: 1.5360x; 1.5360x over previous
//
#include <hip/hip_runtime.h>
#include <math.h>

#define H_ 256
#define W_ 256
#define HW_ 65536
#define BHW_ 131072   // B*H*W, B=2
#define NPC 8388608   // BHW_*64

__device__ __forceinline__ float geluf(float x) {
    const float k0 = 0.7978845608028654f; // sqrt(2/pi)
    return 0.5f * x * (1.f + tanhf(k0 * (x + 0.044715f * x * x * x)));
}
__device__ __forceinline__ float siluf(float x) {
    return x / (1.f + expf(-x));
}

// ---------- fused Poisson: div + 20 Jacobi iters ----------
__global__ __launch_bounds__(256) void k_poisson(const float* __restrict__ x,
                                                 float* __restrict__ gray) {
    __shared__ float u[56 * 57];
    __shared__ float dv[56 * 57];
    int bid = blockIdx.x;
    int b = bid >> 8, t = bid & 255;
    int qy = t >> 4, qx = t & 15;
    int y0i = qy << 4, x0i = qx << 4;
    int ys = max(y0i - 20, 0), ye = min(y0i + 35, 255);
    int xs = max(x0i - 20, 0), xe = min(x0i + 35, 255);
    int Ht = ye - ys + 1, Wt = xe - xs + 1;   // <= 56
    int ty = threadIdx.x >> 5, tx = threadIdx.x & 31;   // 8 x 32
    const float* x5 = x + ((size_t)(b * 9 + 5) << 16);
    const float* x6 = x + ((size_t)(b * 9 + 6) << 16);

    for (int yy = ty; yy < Ht; yy += 8)
        for (int xx = tx; xx < Wt; xx += 32) {
            int gy = ys + yy, gx = xs + xx;
            int i00 = (gy << 8) + gx;
            float v5 = x5[i00], v6 = x6[i00];
            float d = -0.5f * (v5 + v6) + 0.5f * (v5 - v6);
            if (gx > 0) d += 0.5f * (x5[i00 - 1] + x6[i00 - 1]);
            if (gy > 0) d -= 0.5f * (x5[i00 - 256] - x6[i00 - 256]);
            dv[yy * 57 + xx] = d;
            u[yy * 57 + xx] = 0.f;
        }
    __syncthreads();

    float nv[7][2];
    for (int it = 0; it < 20; ++it) {
        #pragma unroll
        for (int i = 0; i < 7; ++i) {
            int yy = ty + i * 8;
            #pragma unroll
            for (int j = 0; j < 2; ++j) {
                int xx = tx + j * 32;
                if (yy < Ht && xx < Wt) {
                    int ym = yy > 0 ? yy - 1 : 0, yp = yy < Ht - 1 ? yy + 1 : Ht - 1;
                    int xm = xx > 0 ? xx - 1 : 0, xp = xx < Wt - 1 ? xx + 1 : Wt - 1;
                    nv[i][j] = (u[ym * 57 + xx] + u[yp * 57 + xx] +
                                u[yy * 57 + xm] + u[yy * 57 + xp] - dv[yy * 57 + xx]) * 0.25f;
                }
            }
        }
        __syncthreads();
        #pragma unroll
        for (int i = 0; i < 7; ++i) {
            int yy = ty + i * 8;
            #pragma unroll
            for (int j = 0; j < 2; ++j) {
                int xx = tx + j * 32;
                if (yy < Ht && xx < Wt) u[yy * 57 + xx] = nv[i][j];
            }
        }
        __syncthreads();
    }

    int oy = threadIdx.x >> 4, ox = threadIdx.x & 15;
    int gy = y0i + oy, gx = x0i + ox;
    gray[((size_t)b << 16) + (gy << 8) + gx] = u[(gy - ys) * 57 + (gx - xs)];
}

// ---------- conv1: 7 -> 32, silu; wave = 64 px, weights via s_load ----------
__global__ __launch_bounds__(256) void k_conv1(const float* __restrict__ x,
        const float* __restrict__ wT, const float* __restrict__ bias,
        float* __restrict__ out) {
    int wid = (blockIdx.x * 256 + threadIdx.x) >> 6;
    int lane = threadIdx.x & 63;
    int pix0 = wid << 6;
    int b = pix0 >> 16, hw0 = pix0 & 65535;
    int h = hw0 >> 8, w0 = hw0 & 255;
    float acc[32];
    #pragma unroll
    for (int o = 0; o < 32; ++o) acc[o] = bias[o];
    const float* inb = x + ((size_t)(b * 9) << 16);
    #pragma unroll
    for (int kh = 0; kh < 3; ++kh) {
        int y = h + kh - 1;
        if ((unsigned)y >= 256u) continue;
        #pragma unroll
        for (int kw = 0; kw < 3; ++kw) {
            int xx = w0 + lane + kw - 1;
            bool valid = (unsigned)xx < 256u;
            int xc = min(max(xx, 0), 255);
            const float* p0 = inb + (y << 8) + xc;
            #pragma unroll
            for (int ci = 0; ci < 7; ++ci) {
                float v = p0[ci << 16];
                v = valid ? v : 0.f;
                const float* wr = wT + (ci * 9 + kh * 3 + kw) * 32;
                #pragma unroll
                for (int o = 0; o < 32; ++o) acc[o] = fmaf(v, wr[o], acc[o]);
            }
        }
    }
    #pragma unroll
    for (int o = 0; o < 32; ++o)
        out[((size_t)(b * 32 + o) << 16) + hw0 + lane] = siluf(acc[o]);
}

// ---------- conv2: 32 -> 32, silu ----------
__global__ __launch_bounds__(256) void k_conv2(const float* __restrict__ in,
        const float* __restrict__ wT, const float* __restrict__ bias,
        float* __restrict__ out) {
    int wid = (blockIdx.x * 256 + threadIdx.x) >> 6;
    int lane = threadIdx.x & 63;
    int pix0 = wid << 6;
    int b = pix0 >> 16, hw0 = pix0 & 65535;
    int h = hw0 >> 8, w0 = hw0 & 255;
    float acc[32];
    #pragma unroll
    for (int o = 0; o < 32; ++o) acc[o] = bias[o];
    const float* inb = in + ((size_t)(b * 32) << 16);
    #pragma unroll
    for (int kh = 0; kh < 3; ++kh) {
        int y = h + kh - 1;
        if ((unsigned)y >= 256u) continue;
        #pragma unroll
        for (int kw = 0; kw < 3; ++kw) {
            int xx = w0 + lane + kw - 1;
            bool valid = (unsigned)xx < 256u;
            int xc = min(max(xx, 0), 255);
            const float* p0 = inb + (y << 8) + xc;
            #pragma unroll 4
            for (int ci = 0; ci < 32; ++ci) {
                float v = p0[ci << 16];
                v = valid ? v : 0.f;
                const float* wr = wT + (ci * 9 + kh * 3 + kw) * 32;
                #pragma unroll
                for (int o = 0; o < 32; ++o) acc[o] = fmaf(v, wr[o], acc[o]);
            }
        }
    }
    #pragma unroll
    for (int o = 0; o < 32; ++o)
        out[((size_t)(b * 32 + o) << 16) + hw0 + lane] = siluf(acc[o]);
}

// ---------- conv3: 32 -> 3 ----------
__global__ __launch_bounds__(256) void k_conv3(const float* __restrict__ in,
        const float* __restrict__ wT, const float* __restrict__ bias,
        float* __restrict__ out) {
    int wid = (blockIdx.x * 256 + threadIdx.x) >> 6;
    int lane = threadIdx.x & 63;
    int pix0 = wid << 6;
    int b = pix0 >> 16, hw0 = pix0 & 65535;
    int h = hw0 >> 8, w0 = hw0 & 255;
    float acc[3];
    #pragma unroll
    for (int o = 0; o < 3; ++o) acc[o] = bias[o];
    const float* inb = in + ((size_t)(b * 32) << 16);
    #pragma unroll
    for (int kh = 0; kh < 3; ++kh) {
        int y = h + kh - 1;
        if ((unsigned)y >= 256u) continue;
        #pragma unroll
        for (int kw = 0; kw < 3; ++kw) {
            int xx = w0 + lane + kw - 1;
            bool valid = (unsigned)xx < 256u;
            int xc = min(max(xx, 0), 255);
            const float* p0 = inb + (y << 8) + xc;
            #pragma unroll 8
            for (int ci = 0; ci < 32; ++ci) {
                float v = p0[ci << 16];
                v = valid ? v : 0.f;
                const float* wr = wT + (ci * 9 + kh * 3 + kw) * 3;
                #pragma unroll
                for (int o = 0; o < 3; ++o) acc[o] = fmaf(v, wr[o], acc[o]);
            }
        }
    }
    #pragma unroll
    for (int o = 0; o < 3; ++o)
        out[((size_t)(b * 3 + o) << 16) + hw0 + lane] = acc[o];
}

// ---------- fused aproj + depthwise + gelu: tile 8x8, halo 1 ----------
__global__ __launch_bounds__(256) void k_adw(const float* __restrict__ x,
        const float* __restrict__ Wa, const float* __restrict__ ba,
        const float* __restrict__ dwW, float* __restrict__ a2) {
    __shared__ float at[100][64];
    int tid = threadIdx.x;
    int bid = blockIdx.x;
    int b = bid >> 10, tb = bid & 1023;
    int ty0 = (tb >> 5) << 3, tx0 = (tb & 31) << 3;
    const float* g0p = x + ((size_t)(b * 9 + 7) << 16);
    const float* g1p = x + ((size_t)(b * 9 + 8) << 16);
    const float* g2p = x + ((size_t)(b * 9 + 5) << 16);
    const float* g3p = x + ((size_t)(b * 9 + 6) << 16);
    int c = tid & 63;
    float w0 = Wa[c], w1 = Wa[64 + c], w2 = Wa[128 + c], w3 = Wa[192 + c];
    float bb = ba[c];
    #pragma unroll
    for (int rep = 0; rep < 25; ++rep) {
        int pos = rep * 4 + (tid >> 6);
        int py = pos / 10, pxx = pos - py * 10;
        int gy = ty0 - 1 + py, gx = tx0 - 1 + pxx;
        float v = 0.f;
        if ((unsigned)gy < 256u && (unsigned)gx < 256u) {
            int ii = (gy << 8) + gx;
            float tv = bb + g0p[ii] * w0 + g1p[ii] * w1 + g2p[ii] * w2 + g3p[ii] * w3;
            v = geluf(tv);
        }
        at[pos][c] = v;
    }
    __syncthreads();
    float dwr[9];
    #pragma unroll
    for (int k = 0; k < 9; ++k) dwr[k] = dwW[k * 64 + c];
    int pgrp = tid >> 6;
    #pragma unroll
    for (int i = 0; i < 16; ++i) {
        int pl = pgrp * 16 + i;
        int pyl = pl >> 3, pxl = pl & 7;
        float s = 0.f;
        #pragma unroll
        for (int kh = 0; kh < 3; ++kh)
            #pragma unroll
            for (int kw = 0; kw < 3; ++kw)
                s += at[(pyl + kh) * 10 + (pxl + kw)][c] * dwr[kh * 3 + kw];
        int gy = ty0 + pyl, gx = tx0 + pxl;
        a2[(((size_t)(b << 16) + (gy << 8) + gx) << 6) + c] = geluf(s);
    }
}

// ---------- xg = core @ W_in + b_in, NHWC ----------
__global__ void k_xproj(const float* __restrict__ x, const float* __restrict__ gray,
                        const float* __restrict__ recon, const float* __restrict__ W,
                        const float* __restrict__ bias, float* __restrict__ xg) {
    int idx = blockIdx.x * blockDim.x + threadIdx.x;
    if (idx >= NPC) return;
    int pix = idx >> 6, c = idx & 63;
    int b = pix >> 16, hw = pix & 65535;
    float c0 = x[((size_t)(b * 9 + 0) << 16) + hw];
    float c1 = x[((size_t)(b * 9 + 1) << 16) + hw];
    float c2 = x[((size_t)(b * 9 + 2) << 16) + hw];
    float c3 = gray[pix];
    float c4 = recon[((size_t)(b * 3 + 0) << 16) + hw];
    float c5 = recon[((size_t)(b * 3 + 1) << 16) + hw];
    float c6 = recon[((size_t)(b * 3 + 2) << 16) + hw];
    float v = bias[c] + c0 * W[c] + c1 * W[64 + c] + c2 * W[128 + c] + c3 * W[192 + c]
            + c4 * W[256 + c] + c5 * W[320 + c] + c6 * W[384 + c];
    xg[idx] = v;
}

// ---------- weight prep: combined [64 x 128] quad layout + out pairs + convT ----------
__device__ __forceinline__ float wcomb(const float* Woff, const float* Wmask, int c, int j) {
    return j < 72 ? Woff[c * 72 + j] : (j < 108 ? Wmask[c * 36 + (j - 72)] : 0.f);
}

__global__ void k_prep(const float* __restrict__ Woff, const float* __restrict__ boff,
                       const float* __restrict__ Wmask, const float* __restrict__ bmask,
                       const float* __restrict__ Wout, const float* __restrict__ rw1,
                       const float* __restrict__ rw2, const float* __restrict__ rw3,
                       float* __restrict__ Wquad, float* __restrict__ Woutp,
                       float* __restrict__ bcomb, float* __restrict__ wT1,
                       float* __restrict__ wT2, float* __restrict__ wT3) {
    int tid = threadIdx.x;
    int lane = tid & 63, i0 = tid >> 6;
    for (int i = i0; i < 32; i += 4) {
        int c0 = 2 * i, c1 = 2 * i + 1;
        float4 q;
        q.x = wcomb(Woff, Wmask, c0, lane);
        q.y = wcomb(Woff, Wmask, c0, lane + 64);
        q.z = wcomb(Woff, Wmask, c1, lane);
        q.w = wcomb(Woff, Wmask, c1, lane + 64);
        ((float4*)Wquad)[i * 64 + lane] = q;
        float2 p;
        p.x = Wout[c0 * 64 + lane];
        p.y = Wout[c1 * 64 + lane];
        ((float2*)Woutp)[i * 64 + lane] = p;
    }
    if (tid < 128) bcomb[tid] = tid < 72 ? boff[tid] : (tid < 108 ? bmask[tid - 72] : 0.f);
    for (int j = tid; j < 63 * 32; j += 256) {
        int jj = j >> 5, o = j & 31;
        wT1[j] = rw1[o * 63 + jj];
    }
    for (int j = tid; j < 288 * 32; j += 256) {
        int jj = j >> 5, o = j & 31;
        wT2[j] = rw2[o * 288 + jj];
    }
    for (int j = tid; j < 288 * 3; j += 256) {
        int jj = j / 3, o = j - jj * 3;
        wT3[j] = rw3[o * 288 + jj];
    }
}

// ---------- DCNv3 core (R3-verbatim): 4 px/wave, 16 per block ----------
__global__ __launch_bounds__(256, 4) void k_dcn(
        const float* __restrict__ a2, const float* __restrict__ xg,
        const float* __restrict__ Wquad, const float* __restrict__ bcomb,
        const float* __restrict__ Woutp, const float* __restrict__ bout,
        float* __restrict__ out) {
    __shared__ __attribute__((aligned(16))) float bufA[16][64];   // a2 staging, then accs
    __shared__ __attribute__((aligned(16))) float offs[16][72];
    __shared__ float pms[16][36];
    __shared__ float invs[16][4];
    __shared__ __attribute__((aligned(16))) float taps[16][36][8]; // then outs[16][65]
    float (*outs)[65] = (float (*)[65])&taps[0][0][0];

    int tid = threadIdx.x;
    int wave = tid >> 6, lane = tid & 63;
    int pixbase = blockIdx.x << 4;
    int b = pixbase >> 16, hw0 = pixbase & 65535;
    int h = hw0 >> 8, w0 = hw0 & 255;
    int pw = wave << 2;

    // A: stage a2 for this wave's 4 pixels
    #pragma unroll
    for (int p = 0; p < 4; ++p)
        bufA[pw + p][lane] = a2[((size_t)(pixbase + pw + p) << 6) + lane];

    // B: combined off+mask projection (cols: lane, 64+lane), 4 px at once
    float acc0[4], acc1[4];
    {
        float b0 = bcomb[lane], b1 = bcomb[64 + lane];
        #pragma unroll
        for (int p = 0; p < 4; ++p) { acc0[p] = b0; acc1[p] = b1; }
        const float4* Wq = (const float4*)Wquad;
        #pragma unroll 4
        for (int i = 0; i < 32; ++i) {
            float4 q = Wq[i * 64 + lane];
            #pragma unroll
            for (int p = 0; p < 4; ++p) {
                float2 av = ((const float2*)&bufA[pw + p][0])[i];
                acc0[p] += av.x * q.x + av.y * q.z;
                acc1[p] += av.x * q.y + av.y * q.w;
            }
        }
    }
    // C: scatter to LDS; exp for mask logits (shift-free softmax)
    #pragma unroll
    for (int p = 0; p < 4; ++p) offs[pw + p][lane] = acc0[p];
    if (lane < 8) {
        #pragma unroll
        for (int p = 0; p < 4; ++p) offs[pw + p][64 + lane] = acc1[p];
    } else if (lane < 44) {
        #pragma unroll
        for (int p = 0; p < 4; ++p) pms[pw + p][lane - 8] = __expf(acc1[p]);
    }
    // D: per (px,g) reciprocal sums (wave-local)
    if (lane < 16) {
        int p = lane >> 2, g = lane & 3;
        const float* m = &pms[pw + p][g * 9];
        float s = m[0]+m[1]+m[2]+m[3]+m[4]+m[5]+m[6]+m[7]+m[8];
        invs[pw + p][g] = 1.f / s;
    }
    // E: tap descriptors, 144 jobs over 64 lanes
    #pragma unroll
    for (int rep = 0; rep < 3; ++rep) {
        int idx = rep * 64 + lane;
        if (idx < 144) {
            int p = idx / 36, j = idx - p * 36;
            int px = pw + p;
            int g = j / 9, k = j - g * 9;
            float2 oxy = ((const float2*)&offs[px][0])[j];
            float pm = pms[px][j] * invs[px][g];
            float ly = (float)(h + k / 3 - 1) + oxy.x;
            float lx = (float)(w0 + px + (k % 3) - 1) + oxy.y;
            float y0f = floorf(ly), x0f = floorf(lx);
            float wy = ly - y0f, wx = lx - x0f;
            int iy0 = (int)y0f, ix0 = (int)x0f;
            int base = b << 16;
            float4 t01, t23;
            {
                int yi = iy0, xi = ix0;
                float wgt = (1.f - wy) * (1.f - wx) * pm;
                if (yi < 0 || yi > 255 || xi < 0 || xi > 255) wgt = 0.f;
                int yc = min(max(yi, 0), 255), xc = min(max(xi, 0), 255);
                t01.x = __int_as_float(base + (yc << 8) + xc); t01.y = wgt;
            }
            {
                int yi = iy0, xi = ix0 + 1;
                float wgt = (1.f - wy) * wx * pm;
                if (yi < 0 || yi > 255 || xi < 0 || xi > 255) wgt = 0.f;
                int yc = min(max(yi, 0), 255), xc = min(max(xi, 0), 255);
                t01.z = __int_as_float(base + (yc << 8) + xc); t01.w = wgt;
            }
            {
                int yi = iy0 + 1, xi = ix0;
                float wgt = wy * (1.f - wx) * pm;
                if (yi < 0 || yi > 255 || xi < 0 || xi > 255) wgt = 0.f;
                int yc = min(max(yi, 0), 255), xc = min(max(xi, 0), 255);
                t23.x = __int_as_float(base + (yc << 8) + xc); t23.y = wgt;
            }
            {
                int yi = iy0 + 1, xi = ix0 + 1;
                float wgt = wy * wx * pm;
                if (yi < 0 || yi > 255 || xi < 0 || xi > 255) wgt = 0.f;
                int yc = min(max(yi, 0), 255), xc = min(max(xi, 0), 255);
                t23.z = __int_as_float(base + (yc << 8) + xc); t23.w = wgt;
            }
            ((float4*)&taps[px][j][0])[0] = t01;
            ((float4*)&taps[px][j][0])[1] = t23;
        }
    }
    // F: gather; lane = channel (g4*16+cg), 4 px per wave
    int g4 = lane >> 4;
    float gacc[4];
    #pragma unroll
    for (int p = 0; p < 4; ++p) {
        float acc = 0.f;
        const float4* tp = (const float4*)&taps[pw + p][g4 * 9][0];
        #pragma unroll
        for (int k = 0; k < 9; ++k) {
            float4 d0 = tp[2 * k], d1 = tp[2 * k + 1];
            acc += d0.y * xg[((size_t)__float_as_int(d0.x) << 6) + lane];
            acc += d0.w * xg[((size_t)__float_as_int(d0.z) << 6) + lane];
            acc += d1.y * xg[((size_t)__float_as_int(d1.x) << 6) + lane];
            acc += d1.w * xg[((size_t)__float_as_int(d1.z) << 6) + lane];
        }
        gacc[p] = acc;
    }
    // G: stage accs (bufA's a2 values are dead)
    #pragma unroll
    for (int p = 0; p < 4; ++p) bufA[pw + p][lane] = gacc[p];

    __syncthreads();   // all waves done with taps/offs/pms before outs overlay

    // H: out projection
    {
        float o[4];
        float bo = bout[lane];
        #pragma unroll
        for (int p = 0; p < 4; ++p) o[p] = bo;
        const float2* Wp = (const float2*)Woutp;
        #pragma unroll 4
        for (int i = 0; i < 32; ++i) {
            float2 pq = Wp[i * 64 + lane];
            #pragma unroll
            for (int p = 0; p < 4; ++p) {
                float2 av = ((const float2*)&bufA[pw + p][0])[i];
                o[p] += av.x * pq.x + av.y * pq.y;
            }
        }
        #pragma unroll
        for (int p = 0; p < 4; ++p) outs[pw + p][lane] = o[p];
    }
    __syncthreads();

    // transposed NCHW write: 16 consecutive w per channel row
    int cq = tid >> 4, px = tid & 15;
    size_t rowb = ((size_t)(b * 64) << 16) + hw0 + px;
    #pragma unroll
    for (int rep = 0; rep < 4; ++rep) {
        int c = cq + rep * 16;
        out[rowb + ((size_t)c << 16)] = outs[px][c];
    }
}

extern "C" void kernel_launch(void* const* d_in, const int* in_sizes, int n_in,
                              void* d_out, int out_size, void* d_ws, size_t ws_size,
                              hipStream_t stream) {
    const float* x      = (const float*)d_in[0];
    const float* rw1    = (const float*)d_in[1];
    const float* rb1    = (const float*)d_in[2];
    const float* rw2    = (const float*)d_in[3];
    const float* rb2    = (const float*)d_in[4];
    const float* rw3    = (const float*)d_in[5];
    const float* rb3    = (const float*)d_in[6];
    const float* W_in   = (const float*)d_in[7];
    const float* b_in   = (const float*)d_in[8];
    const float* W_aop  = (const float*)d_in[9];
    const float* b_aop  = (const float*)d_in[10];
    const float* dw     = (const float*)d_in[11];
    const float* W_off  = (const float*)d_in[12];
    const float* b_off  = (const float*)d_in[13];
    const float* W_mask = (const float*)d_in[14];
    const float* b_mask = (const float*)d_in[15];
    const float* W_out  = (const float*)d_in[16];
    const float* b_out  = (const float*)d_in[17];
    float* out = (float*)d_out;

    // Large arrays FIRST: every offset is a multiple of 131072 floats
    // -> a2/xg pixel rows (256 B) are 256B-aligned (2 cache lines each).
    float* ws = (float*)d_ws;
    float* gray  = ws;                        // 131072
    float* h1    = gray + BHW_;               // 4194304
    float* h2    = h1 + (size_t)BHW_ * 32;    // 4194304
    float* recon = h2 + (size_t)BHW_ * 32;    // 393216
    float* a2    = recon + (size_t)BHW_ * 3;  // 8388608  (256B-aligned)
    float* xg    = a2 + (size_t)NPC;          // 8388608  (256B-aligned)
    float* Wquad = xg + (size_t)NPC;          // 8192
    float* Woutp = Wquad + 8192;              // 4096
    float* bcomb = Woutp + 4096;              // 128
    float* wT1   = bcomb + 128;               // 2016
    float* wT2   = wT1 + 2016;                // 9216
    float* wT3   = wT2 + 9216;                // 864

    dim3 blk(256);

    k_prep<<<dim3(1), blk, 0, stream>>>(W_off, b_off, W_mask, b_mask, W_out,
                                        rw1, rw2, rw3,
                                        Wquad, Woutp, bcomb, wT1, wT2, wT3);
    k_poisson<<<dim3(512), blk, 0, stream>>>(x, gray);
    k_conv1<<<dim3(BHW_ / 256), blk, 0, stream>>>(x, wT1, rb1, h1);
    k_conv2<<<dim3(BHW_ / 256), blk, 0, stream>>>(h1, wT2, rb2, h2);
    k_conv3<<<dim3(BHW_ / 256), blk, 0, stream>>>(h2, wT3, rb3, recon);
    k_adw<<<dim3(BHW_ / 64), blk, 0, stream>>>(x, W_aop, b_aop, dw, a2);
    k_xproj<<<dim3(NPC / 256), blk, 0, stream>>>(x, gray, recon, W_in, b_in, xg);
    k_dcn<<<dim3(BHW_ / 16), blk, 0, stream>>>(a2, xg, Wquad, bcomb, Woutp, b_out, out);
}

// Round 7
// 284.759 us; speedup vs baseline: 1.7814x; 1.1598x over previous
//
#include <hip/hip_runtime.h>
#include <math.h>

#define H_ 256
#define W_ 256
#define HW_ 65536
#define BHW_ 131072   // B*H*W, B=2
#define NPC 8388608   // BHW_*64

__device__ __forceinline__ float geluf(float x) {
    const float k0 = 0.7978845608028654f; // sqrt(2/pi)
    return 0.5f * x * (1.f + tanhf(k0 * (x + 0.044715f * x * x * x)));
}
__device__ __forceinline__ float siluf(float x) {
    return x / (1.f + expf(-x));
}

// ---------- mega kernel: poisson (blocks 0..511) | adw (512..2559) | conv1 (2560..3071) ----------
__global__ __launch_bounds__(256) void k_mega(const float* __restrict__ x,
        float* __restrict__ gray,
        const float* __restrict__ Wa, const float* __restrict__ ba,
        const float* __restrict__ dwW, float* __restrict__ a2,
        const float* __restrict__ wT1, const float* __restrict__ rb1,
        float* __restrict__ h1) {
    __shared__ float smem[6400];
    int bid = blockIdx.x;
    int tid = threadIdx.x;

    if (bid < 512) {
        // ---- Poisson: div + 20 Jacobi iters; 16x16 tile, halo 20 ----
        float* u = smem;            // 56*57 = 3192
        float* dv = smem + 3192;    // 3192
        int b = bid >> 8, t = bid & 255;
        int qy = t >> 4, qx = t & 15;
        int y0i = qy << 4, x0i = qx << 4;
        int ys = max(y0i - 20, 0), ye = min(y0i + 35, 255);
        int xs = max(x0i - 20, 0), xe = min(x0i + 35, 255);
        int Ht = ye - ys + 1, Wt = xe - xs + 1;   // <= 56
        int ty = tid >> 5, tx = tid & 31;   // 8 x 32
        const float* x5 = x + ((size_t)(b * 9 + 5) << 16);
        const float* x6 = x + ((size_t)(b * 9 + 6) << 16);

        for (int yy = ty; yy < Ht; yy += 8)
            for (int xx = tx; xx < Wt; xx += 32) {
                int gy = ys + yy, gx = xs + xx;
                int i00 = (gy << 8) + gx;
                float v5 = x5[i00], v6 = x6[i00];
                float d = -0.5f * (v5 + v6) + 0.5f * (v5 - v6);
                if (gx > 0) d += 0.5f * (x5[i00 - 1] + x6[i00 - 1]);
                if (gy > 0) d -= 0.5f * (x5[i00 - 256] - x6[i00 - 256]);
                dv[yy * 57 + xx] = d;
                u[yy * 57 + xx] = 0.f;
            }
        __syncthreads();

        float nv[7][2];
        for (int it = 0; it < 20; ++it) {
            #pragma unroll
            for (int i = 0; i < 7; ++i) {
                int yy = ty + i * 8;
                #pragma unroll
                for (int j = 0; j < 2; ++j) {
                    int xx = tx + j * 32;
                    if (yy < Ht && xx < Wt) {
                        int ym = yy > 0 ? yy - 1 : 0, yp = yy < Ht - 1 ? yy + 1 : Ht - 1;
                        int xm = xx > 0 ? xx - 1 : 0, xp = xx < Wt - 1 ? xx + 1 : Wt - 1;
                        nv[i][j] = (u[ym * 57 + xx] + u[yp * 57 + xx] +
                                    u[yy * 57 + xm] + u[yy * 57 + xp] - dv[yy * 57 + xx]) * 0.25f;
                    }
                }
            }
            __syncthreads();
            #pragma unroll
            for (int i = 0; i < 7; ++i) {
                int yy = ty + i * 8;
                #pragma unroll
                for (int j = 0; j < 2; ++j) {
                    int xx = tx + j * 32;
                    if (yy < Ht && xx < Wt) u[yy * 57 + xx] = nv[i][j];
                }
            }
            __syncthreads();
        }

        int oy = tid >> 4, ox = tid & 15;
        int gy = y0i + oy, gx = x0i + ox;
        gray[((size_t)b << 16) + (gy << 8) + gx] = u[(gy - ys) * 57 + (gx - xs)];

    } else if (bid < 2560) {
        // ---- fused aproj + depthwise + gelu: tile 8x8, halo 1 ----
        float (*at)[64] = (float (*)[64])smem;   // 100*64 = 6400
        int abid = bid - 512;
        int b = abid >> 10, tb = abid & 1023;
        int ty0 = (tb >> 5) << 3, tx0 = (tb & 31) << 3;
        const float* g0p = x + ((size_t)(b * 9 + 7) << 16);
        const float* g1p = x + ((size_t)(b * 9 + 8) << 16);
        const float* g2p = x + ((size_t)(b * 9 + 5) << 16);
        const float* g3p = x + ((size_t)(b * 9 + 6) << 16);
        int c = tid & 63;
        float w0 = Wa[c], w1 = Wa[64 + c], w2 = Wa[128 + c], w3 = Wa[192 + c];
        float bb = ba[c];
        #pragma unroll
        for (int rep = 0; rep < 25; ++rep) {
            int pos = rep * 4 + (tid >> 6);
            int py = pos / 10, pxx = pos - py * 10;
            int gy = ty0 - 1 + py, gx = tx0 - 1 + pxx;
            float v = 0.f;
            if ((unsigned)gy < 256u && (unsigned)gx < 256u) {
                int ii = (gy << 8) + gx;
                float tv = bb + g0p[ii] * w0 + g1p[ii] * w1 + g2p[ii] * w2 + g3p[ii] * w3;
                v = geluf(tv);
            }
            at[pos][c] = v;
        }
        __syncthreads();
        float dwr[9];
        #pragma unroll
        for (int k = 0; k < 9; ++k) dwr[k] = dwW[k * 64 + c];
        int pgrp = tid >> 6;
        #pragma unroll
        for (int i = 0; i < 16; ++i) {
            int pl = pgrp * 16 + i;
            int pyl = pl >> 3, pxl = pl & 7;
            float s = 0.f;
            #pragma unroll
            for (int kh = 0; kh < 3; ++kh)
                #pragma unroll
                for (int kw = 0; kw < 3; ++kw)
                    s += at[(pyl + kh) * 10 + (pxl + kw)][c] * dwr[kh * 3 + kw];
            int gy = ty0 + pyl, gx = tx0 + pxl;
            a2[(((size_t)(b << 16) + (gy << 8) + gx) << 6) + c] = geluf(s);
        }

    } else {
        // ---- conv1: 7 -> 32, silu; wave = 64 px, weights via s_load ----
        int cbid = bid - 2560;
        int wid = (cbid * 256 + tid) >> 6;
        int lane = tid & 63;
        int pix0 = wid << 6;
        int b = pix0 >> 16, hw0 = pix0 & 65535;
        int h = hw0 >> 8, w0 = hw0 & 255;
        float acc[32];
        #pragma unroll
        for (int o = 0; o < 32; ++o) acc[o] = rb1[o];
        const float* inb = x + ((size_t)(b * 9) << 16);
        #pragma unroll
        for (int kh = 0; kh < 3; ++kh) {
            int y = h + kh - 1;
            if ((unsigned)y >= 256u) continue;
            #pragma unroll
            for (int kw = 0; kw < 3; ++kw) {
                int xx = w0 + lane + kw - 1;
                bool valid = (unsigned)xx < 256u;
                int xc = min(max(xx, 0), 255);
                const float* p0 = inb + (y << 8) + xc;
                #pragma unroll
                for (int ci = 0; ci < 7; ++ci) {
                    float v = p0[ci << 16];
                    v = valid ? v : 0.f;
                    const float* wr = wT1 + (ci * 9 + kh * 3 + kw) * 32;
                    #pragma unroll
                    for (int o = 0; o < 32; ++o) acc[o] = fmaf(v, wr[o], acc[o]);
                }
            }
        }
        #pragma unroll
        for (int o = 0; o < 32; ++o)
            h1[((size_t)(b * 32 + o) << 16) + hw0 + lane] = siluf(acc[o]);
    }
}

// ---------- conv2: 32 -> 32, silu ----------
__global__ __launch_bounds__(256) void k_conv2(const float* __restrict__ in,
        const float* __restrict__ wT, const float* __restrict__ bias,
        float* __restrict__ out) {
    int wid = (blockIdx.x * 256 + threadIdx.x) >> 6;
    int lane = threadIdx.x & 63;
    int pix0 = wid << 6;
    int b = pix0 >> 16, hw0 = pix0 & 65535;
    int h = hw0 >> 8, w0 = hw0 & 255;
    float acc[32];
    #pragma unroll
    for (int o = 0; o < 32; ++o) acc[o] = bias[o];
    const float* inb = in + ((size_t)(b * 32) << 16);
    #pragma unroll
    for (int kh = 0; kh < 3; ++kh) {
        int y = h + kh - 1;
        if ((unsigned)y >= 256u) continue;
        #pragma unroll
        for (int kw = 0; kw < 3; ++kw) {
            int xx = w0 + lane + kw - 1;
            bool valid = (unsigned)xx < 256u;
            int xc = min(max(xx, 0), 255);
            const float* p0 = inb + (y << 8) + xc;
            #pragma unroll 4
            for (int ci = 0; ci < 32; ++ci) {
                float v = p0[ci << 16];
                v = valid ? v : 0.f;
                const float* wr = wT + (ci * 9 + kh * 3 + kw) * 32;
                #pragma unroll
                for (int o = 0; o < 32; ++o) acc[o] = fmaf(v, wr[o], acc[o]);
            }
        }
    }
    #pragma unroll
    for (int o = 0; o < 32; ++o)
        out[((size_t)(b * 32 + o) << 16) + hw0 + lane] = siluf(acc[o]);
}

// ---------- conv3: 32 -> 3 ----------
__global__ __launch_bounds__(256) void k_conv3(const float* __restrict__ in,
        const float* __restrict__ wT, const float* __restrict__ bias,
        float* __restrict__ out) {
    int wid = (blockIdx.x * 256 + threadIdx.x) >> 6;
    int lane = threadIdx.x & 63;
    int pix0 = wid << 6;
    int b = pix0 >> 16, hw0 = pix0 & 65535;
    int h = hw0 >> 8, w0 = hw0 & 255;
    float acc[3];
    #pragma unroll
    for (int o = 0; o < 3; ++o) acc[o] = bias[o];
    const float* inb = in + ((size_t)(b * 32) << 16);
    #pragma unroll
    for (int kh = 0; kh < 3; ++kh) {
        int y = h + kh - 1;
        if ((unsigned)y >= 256u) continue;
        #pragma unroll
        for (int kw = 0; kw < 3; ++kw) {
            int xx = w0 + lane + kw - 1;
            bool valid = (unsigned)xx < 256u;
            int xc = min(max(xx, 0), 255);
            const float* p0 = inb + (y << 8) + xc;
            #pragma unroll 8
            for (int ci = 0; ci < 32; ++ci) {
                float v = p0[ci << 16];
                v = valid ? v : 0.f;
                const float* wr = wT + (ci * 9 + kh * 3 + kw) * 3;
                #pragma unroll
                for (int o = 0; o < 3; ++o) acc[o] = fmaf(v, wr[o], acc[o]);
            }
        }
    }
    #pragma unroll
    for (int o = 0; o < 3; ++o)
        out[((size_t)(b * 3 + o) << 16) + hw0 + lane] = acc[o];
}

// ---------- xg = core @ W_in + b_in, NHWC ----------
__global__ void k_xproj(const float* __restrict__ x, const float* __restrict__ gray,
                        const float* __restrict__ recon, const float* __restrict__ W,
                        const float* __restrict__ bias, float* __restrict__ xg) {
    int idx = blockIdx.x * blockDim.x + threadIdx.x;
    if (idx >= NPC) return;
    int pix = idx >> 6, c = idx & 63;
    int b = pix >> 16, hw = pix & 65535;
    float c0 = x[((size_t)(b * 9 + 0) << 16) + hw];
    float c1 = x[((size_t)(b * 9 + 1) << 16) + hw];
    float c2 = x[((size_t)(b * 9 + 2) << 16) + hw];
    float c3 = gray[pix];
    float c4 = recon[((size_t)(b * 3 + 0) << 16) + hw];
    float c5 = recon[((size_t)(b * 3 + 1) << 16) + hw];
    float c6 = recon[((size_t)(b * 3 + 2) << 16) + hw];
    float v = bias[c] + c0 * W[c] + c1 * W[64 + c] + c2 * W[128 + c] + c3 * W[192 + c]
            + c4 * W[256 + c] + c5 * W[320 + c] + c6 * W[384 + c];
    xg[idx] = v;
}

// ---------- weight prep: combined [64 x 128] quad layout + out pairs + convT ----------
__device__ __forceinline__ float wcomb(const float* Woff, const float* Wmask, int c, int j) {
    return j < 72 ? Woff[c * 72 + j] : (j < 108 ? Wmask[c * 36 + (j - 72)] : 0.f);
}

__global__ void k_prep(const float* __restrict__ Woff, const float* __restrict__ boff,
                       const float* __restrict__ Wmask, const float* __restrict__ bmask,
                       const float* __restrict__ Wout, const float* __restrict__ rw1,
                       const float* __restrict__ rw2, const float* __restrict__ rw3,
                       float* __restrict__ Wquad, float* __restrict__ Woutp,
                       float* __restrict__ bcomb, float* __restrict__ wT1,
                       float* __restrict__ wT2, float* __restrict__ wT3) {
    int tid = threadIdx.x;
    int lane = tid & 63, i0 = tid >> 6;
    for (int i = i0; i < 32; i += 4) {
        int c0 = 2 * i, c1 = 2 * i + 1;
        float4 q;
        q.x = wcomb(Woff, Wmask, c0, lane);
        q.y = wcomb(Woff, Wmask, c0, lane + 64);
        q.z = wcomb(Woff, Wmask, c1, lane);
        q.w = wcomb(Woff, Wmask, c1, lane + 64);
        ((float4*)Wquad)[i * 64 + lane] = q;
        float2 p;
        p.x = Wout[c0 * 64 + lane];
        p.y = Wout[c1 * 64 + lane];
        ((float2*)Woutp)[i * 64 + lane] = p;
    }
    if (tid < 128) bcomb[tid] = tid < 72 ? boff[tid] : (tid < 108 ? bmask[tid - 72] : 0.f);
    for (int j = tid; j < 63 * 32; j += 256) {
        int jj = j >> 5, o = j & 31;
        wT1[j] = rw1[o * 63 + jj];
    }
    for (int j = tid; j < 288 * 32; j += 256) {
        int jj = j >> 5, o = j & 31;
        wT2[j] = rw2[o * 288 + jj];
    }
    for (int j = tid; j < 288 * 3; j += 256) {
        int jj = j / 3, o = j - jj * 3;
        wT3[j] = rw3[o * 288 + jj];
    }
}

// ---------- DCNv3 core: R6 base + byte-offset saddr gather (single change) ----------
__global__ __launch_bounds__(256, 4) void k_dcn(
        const float* __restrict__ a2, const float* __restrict__ xg,
        const float* __restrict__ Wquad, const float* __restrict__ bcomb,
        const float* __restrict__ Woutp, const float* __restrict__ bout,
        float* __restrict__ out) {
    __shared__ __attribute__((aligned(16))) float bufA[16][64];   // a2 staging, then accs
    __shared__ __attribute__((aligned(16))) float offs[16][72];
    __shared__ float pms[16][36];
    __shared__ float invs[16][4];
    __shared__ __attribute__((aligned(16))) float taps[16][36][8]; // then outs[16][65]
    float (*outs)[65] = (float (*)[65])&taps[0][0][0];

    int tid = threadIdx.x;
    int wave = tid >> 6, lane = tid & 63;
    int pixbase = blockIdx.x << 4;
    int b = pixbase >> 16, hw0 = pixbase & 65535;
    int h = hw0 >> 8, w0 = hw0 & 255;
    int pw = wave << 2;

    // A: stage a2 for this wave's 4 pixels
    #pragma unroll
    for (int p = 0; p < 4; ++p)
        bufA[pw + p][lane] = a2[((size_t)(pixbase + pw + p) << 6) + lane];

    // B: combined off+mask projection (cols: lane, 64+lane), 4 px at once
    float acc0[4], acc1[4];
    {
        float b0 = bcomb[lane], b1 = bcomb[64 + lane];
        #pragma unroll
        for (int p = 0; p < 4; ++p) { acc0[p] = b0; acc1[p] = b1; }
        const float4* Wq = (const float4*)Wquad;
        #pragma unroll 4
        for (int i = 0; i < 32; ++i) {
            float4 q = Wq[i * 64 + lane];
            #pragma unroll
            for (int p = 0; p < 4; ++p) {
                float2 av = ((const float2*)&bufA[pw + p][0])[i];
                acc0[p] += av.x * q.x + av.y * q.z;
                acc1[p] += av.x * q.y + av.y * q.w;
            }
        }
    }
    // C: scatter to LDS; exp for mask logits (shift-free softmax)
    #pragma unroll
    for (int p = 0; p < 4; ++p) offs[pw + p][lane] = acc0[p];
    if (lane < 8) {
        #pragma unroll
        for (int p = 0; p < 4; ++p) offs[pw + p][64 + lane] = acc1[p];
    } else if (lane < 44) {
        #pragma unroll
        for (int p = 0; p < 4; ++p) pms[pw + p][lane - 8] = __expf(acc1[p]);
    }
    // D: per (px,g) reciprocal sums (wave-local)
    if (lane < 16) {
        int p = lane >> 2, g = lane & 3;
        const float* m = &pms[pw + p][g * 9];
        float s = m[0]+m[1]+m[2]+m[3]+m[4]+m[5]+m[6]+m[7]+m[8];
        invs[pw + p][g] = 1.f / s;
    }
    // E: tap descriptors (BYTE offsets = spatial<<8), 144 jobs over 64 lanes
    #pragma unroll
    for (int rep = 0; rep < 3; ++rep) {
        int idx = rep * 64 + lane;
        if (idx < 144) {
            int p = idx / 36, j = idx - p * 36;
            int px = pw + p;
            int g = j / 9, k = j - g * 9;
            float2 oxy = ((const float2*)&offs[px][0])[j];
            float pm = pms[px][j] * invs[px][g];
            float ly = (float)(h + k / 3 - 1) + oxy.x;
            float lx = (float)(w0 + px + (k % 3) - 1) + oxy.y;
            float y0f = floorf(ly), x0f = floorf(lx);
            float wy = ly - y0f, wx = lx - x0f;
            int iy0 = (int)y0f, ix0 = (int)x0f;
            int base = b << 16;
            float4 t01, t23;
            {
                int yi = iy0, xi = ix0;
                float wgt = (1.f - wy) * (1.f - wx) * pm;
                if (yi < 0 || yi > 255 || xi < 0 || xi > 255) wgt = 0.f;
                int yc = min(max(yi, 0), 255), xc = min(max(xi, 0), 255);
                t01.x = __int_as_float((base + (yc << 8) + xc) << 8); t01.y = wgt;
            }
            {
                int yi = iy0, xi = ix0 + 1;
                float wgt = (1.f - wy) * wx * pm;
                if (yi < 0 || yi > 255 || xi < 0 || xi > 255) wgt = 0.f;
                int yc = min(max(yi, 0), 255), xc = min(max(xi, 0), 255);
                t01.z = __int_as_float((base + (yc << 8) + xc) << 8); t01.w = wgt;
            }
            {
                int yi = iy0 + 1, xi = ix0;
                float wgt = wy * (1.f - wx) * pm;
                if (yi < 0 || yi > 255 || xi < 0 || xi > 255) wgt = 0.f;
                int yc = min(max(yi, 0), 255), xc = min(max(xi, 0), 255);
                t23.x = __int_as_float((base + (yc << 8) + xc) << 8); t23.y = wgt;
            }
            {
                int yi = iy0 + 1, xi = ix0 + 1;
                float wgt = wy * wx * pm;
                if (yi < 0 || yi > 255 || xi < 0 || xi > 255) wgt = 0.f;
                int yc = min(max(yi, 0), 255), xc = min(max(xi, 0), 255);
                t23.z = __int_as_float((base + (yc << 8) + xc) << 8); t23.w = wgt;
            }
            ((float4*)&taps[px][j][0])[0] = t01;
            ((float4*)&taps[px][j][0])[1] = t23;
        }
    }
    // F: gather; lane = channel (g4*16+cg), 4 px per wave; saddr + 32-bit byte offset
    int g4 = lane >> 4;
    const char* xgb = (const char*)xg;
    unsigned lane4 = (unsigned)(lane << 2);
    float gacc[4];
    #pragma unroll
    for (int p = 0; p < 4; ++p) {
        float acc = 0.f;
        const float4* tp = (const float4*)&taps[pw + p][g4 * 9][0];
        #pragma unroll
        for (int k = 0; k < 9; ++k) {
            float4 d0 = tp[2 * k], d1 = tp[2 * k + 1];
            acc = fmaf(d0.y, *(const float*)(xgb + ((unsigned)__float_as_int(d0.x) + lane4)), acc);
            acc = fmaf(d0.w, *(const float*)(xgb + ((unsigned)__float_as_int(d0.z) + lane4)), acc);
            acc = fmaf(d1.y, *(const float*)(xgb + ((unsigned)__float_as_int(d1.x) + lane4)), acc);
            acc = fmaf(d1.w, *(const float*)(xgb + ((unsigned)__float_as_int(d1.z) + lane4)), acc);
        }
        gacc[p] = acc;
    }
    // G: stage accs (bufA's a2 values are dead)
    #pragma unroll
    for (int p = 0; p < 4; ++p) bufA[pw + p][lane] = gacc[p];

    __syncthreads();   // all waves done with taps/offs/pms before outs overlay

    // H: out projection
    {
        float o[4];
        float bo = bout[lane];
        #pragma unroll
        for (int p = 0; p < 4; ++p) o[p] = bo;
        const float2* Wp = (const float2*)Woutp;
        #pragma unroll 4
        for (int i = 0; i < 32; ++i) {
            float2 pq = Wp[i * 64 + lane];
            #pragma unroll
            for (int p = 0; p < 4; ++p) {
                float2 av = ((const float2*)&bufA[pw + p][0])[i];
                o[p] += av.x * pq.x + av.y * pq.y;
            }
        }
        #pragma unroll
        for (int p = 0; p < 4; ++p) outs[pw + p][lane] = o[p];
    }
    __syncthreads();

    // transposed NCHW write: 16 consecutive w per channel row
    int cq = tid >> 4, px = tid & 15;
    size_t rowb = ((size_t)(b * 64) << 16) + hw0 + px;
    #pragma unroll
    for (int rep = 0; rep < 4; ++rep) {
        int c = cq + rep * 16;
        out[rowb + ((size_t)c << 16)] = outs[px][c];
    }
}

extern "C" void kernel_launch(void* const* d_in, const int* in_sizes, int n_in,
                              void* d_out, int out_size, void* d_ws, size_t ws_size,
                              hipStream_t stream) {
    const float* x      = (const float*)d_in[0];
    const float* rw1    = (const float*)d_in[1];
    const float* rb1    = (const float*)d_in[2];
    const float* rw2    = (const float*)d_in[3];
    const float* rb2    = (const float*)d_in[4];
    const float* rw3    = (const float*)d_in[5];
    const float* rb3    = (const float*)d_in[6];
    const float* W_in   = (const float*)d_in[7];
    const float* b_in   = (const float*)d_in[8];
    const float* W_aop  = (const float*)d_in[9];
    const float* b_aop  = (const float*)d_in[10];
    const float* dw     = (const float*)d_in[11];
    const float* W_off  = (const float*)d_in[12];
    const float* b_off  = (const float*)d_in[13];
    const float* W_mask = (const float*)d_in[14];
    const float* b_mask = (const float*)d_in[15];
    const float* W_out  = (const float*)d_in[16];
    const float* b_out  = (const float*)d_in[17];
    float* out = (float*)d_out;

    // Large arrays FIRST: every offset is a multiple of 131072 floats
    // -> a2/xg pixel rows (256 B) are 256B-aligned. (R4/R5 broke this: 4x FETCH.)
    float* ws = (float*)d_ws;
    float* gray  = ws;                        // 131072
    float* h1    = gray + BHW_;               // 4194304
    float* h2    = h1 + (size_t)BHW_ * 32;    // 4194304
    float* recon = h2 + (size_t)BHW_ * 32;    // 393216
    float* a2    = recon + (size_t)BHW_ * 3;  // 8388608  (256B-aligned)
    float* xg    = a2 + (size_t)NPC;          // 8388608  (256B-aligned)
    float* Wquad = xg + (size_t)NPC;          // 8192
    float* Woutp = Wquad + 8192;              // 4096
    float* bcomb = Woutp + 4096;              // 128
    float* wT1   = bcomb + 128;               // 2016
    float* wT2   = wT1 + 2016;                // 9216
    float* wT3   = wT2 + 9216;                // 864

    dim3 blk(256);

    k_prep<<<dim3(1), blk, 0, stream>>>(W_off, b_off, W_mask, b_mask, W_out,
                                        rw1, rw2, rw3,
                                        Wquad, Woutp, bcomb, wT1, wT2, wT3);
    k_mega<<<dim3(3072), blk, 0, stream>>>(x, gray, W_aop, b_aop, dw, a2,
                                           wT1, rb1, h1);
    k_conv2<<<dim3(BHW_ / 256), blk, 0, stream>>>(h1, wT2, rb2, h2);
    k_conv3<<<dim3(BHW_ / 256), blk, 0, stream>>>(h2, wT3, rb3, recon);
    k_xproj<<<dim3(NPC / 256), blk, 0, stream>>>(x, gray, recon, W_in, b_in, xg);
    k_dcn<<<dim3(BHW_ / 16), blk, 0, stream>>>(a2, xg, Wquad, bcomb, Woutp, b_out, out);
}